// Round 1
// baseline (170.028 us; speedup 1.0000x reference)
//
#include <hip/hip_runtime.h>
#include <hip/hip_fp16.h>

// DenseMultiRangeAttention on MI355X (gfx950)
// B=2, C=96, H=W=64, heads=4, d=24, ranges {7,9,11}
//
// Pipeline:
//   K0 transpose_wo : wo (96x288) -> woT (288x96) f32
//   K1 qkv          : x (B,96,HW) f32 -> Q/K/V (B*HW, 96) f16
//   K2 attn         : nested-ring sweep over 11x11, snapshots at 7/9/11
//                     -> att (B*HW, 288) f16, channel = h*72 + r*24 + dd
//   K3 proj         : out[(b*96+o)*HW+p] = bo[o] + sum_c woT[c][o]*att[p][c]

#define HW    4096
#define NH    4
#define D     24
#define CC    96
#define C3    288
#define BATCH 2

#define TS    8        // attn tile side
#define HALO  5        // max pad (k=11)
#define SW    18       // staged tile side = TS + 2*HALO
#define SPIX  324      // SW*SW
#define PSTR  40       // f16 elems per staged pixel (80B, 5x 16B chunks -> bank-clean)

#define INV_SCALE 0.20412414523193151f  // 1/sqrt(24)

typedef unsigned short u16;
typedef _Float16 h2f __attribute__((ext_vector_type(2)));

__device__ __forceinline__ float fdot2h(unsigned int a, unsigned int b, float c) {
#if __has_builtin(__builtin_amdgcn_fdot2)
    return __builtin_amdgcn_fdot2(__builtin_bit_cast(h2f, a),
                                  __builtin_bit_cast(h2f, b), c, false);
#else
    float2 fa = __half22float2(__builtin_bit_cast(__half2, a));
    float2 fb = __half22float2(__builtin_bit_cast(__half2, b));
    return fmaf(fa.x, fb.x, fmaf(fa.y, fb.y, c));
#endif
}

// ---------------------------------------------------------------- K0
__global__ void transpose_wo(const float* __restrict__ wo, float* __restrict__ woT) {
    int idx = blockIdx.x * 256 + threadIdx.x;
    if (idx < CC * C3) {
        int o = idx % CC;       // woT[idx] with idx = c*96 + o
        int c = idx / CC;
        woT[idx] = wo[o * C3 + c];
    }
}

// ---------------------------------------------------------------- K1
// grid (128, 3) block 256. Each block: 64 pixels, one matrix (Q/K/V).
// Wave w computes output channels [w*24, w*24+24) for its lane's pixel.
__global__ __launch_bounds__(256) void qkv_kernel(
    const float* __restrict__ x,
    const float* __restrict__ wq, const float* __restrict__ bq,
    const float* __restrict__ wk, const float* __restrict__ bk,
    const float* __restrict__ wv, const float* __restrict__ bv,
    u16* __restrict__ Qh, u16* __restrict__ Kh, u16* __restrict__ Vh)
{
    int t   = threadIdx.x;
    int mat = blockIdx.y;
    const float* w    = (mat == 0) ? wq : (mat == 1) ? wk : wv;
    const float* bias = (mat == 0) ? bq : (mat == 1) ? bk : bv;
    u16* dst          = (mat == 0) ? Qh : (mat == 1) ? Kh : Vh;

    int gp = blockIdx.x * 64 + (t & 63);
    int b  = gp >> 12;           // /4096
    int p  = gp & 4095;
    int o0 = __builtin_amdgcn_readfirstlane(t >> 6) * D;  // wave-uniform -> s_loads for w

    float xv[CC];
    #pragma unroll
    for (int c = 0; c < CC; ++c)
        xv[c] = x[(b * CC + c) * HW + p];

    float a[D];
    #pragma unroll
    for (int j = 0; j < D; ++j) {
        float acc = bias[o0 + j];
        #pragma unroll
        for (int c = 0; c < CC; ++c)
            acc = fmaf(w[(o0 + j) * CC + c], xv[c], acc);
        a[j] = acc;
    }

    unsigned int u[12];
    #pragma unroll
    for (int i = 0; i < 12; ++i)
        u[i] = __builtin_bit_cast(unsigned int, __floats2half2_rn(a[2*i], a[2*i+1]));

    uint4* dp = (uint4*)(dst + (size_t)gp * CC + o0);
    dp[0] = make_uint4(u[0], u[1], u[2],  u[3]);
    dp[1] = make_uint4(u[4], u[5], u[6],  u[7]);
    dp[2] = make_uint4(u[8], u[9], u[10], u[11]);
}

// ---------------------------------------------------------------- K2
// grid (8,8,8) block 64 (1 wave). z = b*4+h. Tile 8x8 pixels, halo 5.
// K/V f16 staged in LDS (zeros in OOB halo == reference zero-pad:
// score 0 -> exp(0)=1 in denominator, V=0 in numerator).
__global__ __launch_bounds__(64) void attn_kernel(
    const u16* __restrict__ Qh, const u16* __restrict__ Kh,
    const u16* __restrict__ Vh, u16* __restrict__ att)
{
    __shared__ __align__(16) u16 Ks[SPIX * PSTR];
    __shared__ __align__(16) u16 Vs[SPIX * PSTR];

    int t  = threadIdx.x;
    int bh = blockIdx.z;
    int b  = bh >> 2, h = bh & 3;
    int x0 = blockIdx.x * TS, y0 = blockIdx.y * TS;

    // ---- stage K,V tile (+halo) as f16, zeros outside image
    for (int sp = t; sp < SPIX; sp += 64) {
        int sy = sp / SW, sx = sp - sy * SW;
        int gy = y0 + sy - HALO, gx = x0 + sx - HALO;
        uint4 k0 = make_uint4(0,0,0,0), k1 = k0, k2 = k0;
        uint4 v0 = k0, v1 = k0, v2 = k0;
        if ((unsigned)gy < 64u && (unsigned)gx < 64u) {
            size_t base = ((size_t)(b * HW + gy * 64 + gx) * CC + h * D);
            const uint4* ksrc = (const uint4*)(Kh + base);
            const uint4* vsrc = (const uint4*)(Vh + base);
            k0 = ksrc[0]; k1 = ksrc[1]; k2 = ksrc[2];
            v0 = vsrc[0]; v1 = vsrc[1]; v2 = vsrc[2];
        }
        uint4* kd = (uint4*)(Ks + sp * PSTR);
        uint4* vd = (uint4*)(Vs + sp * PSTR);
        kd[0] = k0; kd[1] = k1; kd[2] = k2;
        vd[0] = v0; vd[1] = v1; vd[2] = v2;
    }
    __syncthreads();

    int ty = t >> 3, tx = t & 7;
    int gy = y0 + ty, gx = x0 + tx;
    int gp = b * HW + gy * 64 + gx;

    // ---- Q for this lane's pixel (12 packed f16 pairs)
    unsigned int q[12];
    {
        const uint4* qs = (const uint4*)(Qh + (size_t)gp * CC + h * D);
        uint4 a = qs[0], bb = qs[1], c = qs[2];
        q[0]=a.x;  q[1]=a.y;  q[2]=a.z;  q[3]=a.w;
        q[4]=bb.x; q[5]=bb.y; q[6]=bb.z; q[7]=bb.w;
        q[8]=c.x;  q[9]=c.y;  q[10]=c.z; q[11]=c.w;
    }

    float acc[D];
    #pragma unroll
    for (int j = 0; j < D; ++j) acc[j] = 0.f;
    float l  = 0.f;
    int   cp = (ty + HALO) * SW + (tx + HALO);

    auto body = [&](int di, int dj) {
        int sp = cp + di * SW + dj;
        const uint4* kp = (const uint4*)(Ks + sp * PSTR);
        uint4 k0 = kp[0], k1 = kp[1], k2 = kp[2];
        unsigned int ku[12] = {k0.x,k0.y,k0.z,k0.w, k1.x,k1.y,k1.z,k1.w, k2.x,k2.y,k2.z,k2.w};
        float s = 0.f;
        #pragma unroll
        for (int i = 0; i < 12; ++i) s = fdot2h(ku[i], q[i], s);
        float pw = __expf(s * INV_SCALE);   // no-max softmax: scores are O(1), f32-safe
        l += pw;
        const uint4* vp = (const uint4*)(Vs + sp * PSTR);
        uint4 v0 = vp[0], v1 = vp[1], v2 = vp[2];
        unsigned int vu[12] = {v0.x,v0.y,v0.z,v0.w, v1.x,v1.y,v1.z,v1.w, v2.x,v2.y,v2.z,v2.w};
        #pragma unroll
        for (int i = 0; i < 12; ++i) {
            float2 f = __half22float2(__builtin_bit_cast(__half2, vu[i]));
            acc[2*i]   = fmaf(pw, f.x, acc[2*i]);
            acc[2*i+1] = fmaf(pw, f.y, acc[2*i+1]);
        }
    };

    auto writeout = [&](int r) {
        float rl = 1.0f / l;
        unsigned int u[12];
        #pragma unroll
        for (int i = 0; i < 12; ++i)
            u[i] = __builtin_bit_cast(unsigned int,
                       __floats2half2_rn(acc[2*i] * rl, acc[2*i+1] * rl));
        uint4* dp = (uint4*)(att + (size_t)gp * C3 + h * 72 + r * D);
        dp[0] = make_uint4(u[0], u[1], u[2],  u[3]);
        dp[1] = make_uint4(u[4], u[5], u[6],  u[7]);
        dp[2] = make_uint4(u[8], u[9], u[10], u[11]);
    };

    // ---- nested rings: 7x7 core, then ring to 9x9, then ring to 11x11.
    // Numerator/denominator are prefix sums (no-max softmax is linear).
    for (int di = -3; di <= 3; ++di)
        for (int dj = -3; dj <= 3; ++dj) body(di, dj);
    writeout(0);

    for (int dj = -4; dj <= 4; ++dj) { body(-4, dj); body(4, dj); }
    for (int di = -3; di <= 3; ++di) { body(di, -4); body(di, 4); }
    writeout(1);

    for (int dj = -5; dj <= 5; ++dj) { body(-5, dj); body(5, dj); }
    for (int di = -4; di <= 4; ++di) { body(di, -5); body(di, 5); }
    writeout(2);
}

// ---------------------------------------------------------------- K3
// grid (128, 2) block 256. Tile = 64 pixels. att tile staged TRANSPOSED
// [288][65] f32 in LDS (bank-clean broadcast reads). Wave-chunk of 12 outs.
#define K3_PAD 65
__global__ __launch_bounds__(256) void proj_kernel(
    const u16* __restrict__ att, const float* __restrict__ woT,
    const float* __restrict__ bo, float* __restrict__ out)
{
    __shared__ float s[C3 * K3_PAD];  // 74880 B

    int t   = threadIdx.x;
    int gp0 = blockIdx.x * 64;

    const uint4* src = (const uint4*)(att + (size_t)gp0 * C3);
    for (int u = t; u < 2304; u += 256) {     // 64 px * 288 f16 / 8 per uint4
        uint4 v  = src[u];
        int flat = u * 8;
        int pl   = flat / C3;
        int c    = flat - pl * C3;
        unsigned int uu[4] = {v.x, v.y, v.z, v.w};
        #pragma unroll
        for (int i = 0; i < 4; ++i) {
            float2 f = __half22float2(__builtin_bit_cast(__half2, uu[i]));
            s[(c + 2*i)     * K3_PAD + pl] = f.x;
            s[(c + 2*i + 1) * K3_PAD + pl] = f.y;
        }
    }
    __syncthreads();

    int pl    = t & 63;
    int chunk = __builtin_amdgcn_readfirstlane(t >> 6) + 4 * blockIdx.y;
    int o0    = chunk * 12;
    int gp    = gp0 + pl;
    int b     = gp >> 12, p = gp & 4095;

    float acc[12];
    #pragma unroll
    for (int j = 0; j < 12; ++j) acc[j] = bo[o0 + j];

    for (int c = 0; c < C3; ++c) {
        float av = s[c * K3_PAD + pl];
        #pragma unroll
        for (int j = 0; j < 12; ++j)
            acc[j] = fmaf(woT[c * CC + o0 + j], av, acc[j]);
    }

    #pragma unroll
    for (int j = 0; j < 12; ++j)
        out[(size_t)(b * CC + o0 + j) * HW + p] = acc[j];
}

// ---------------------------------------------------------------- launch
extern "C" void kernel_launch(void* const* d_in, const int* in_sizes, int n_in,
                              void* d_out, int out_size, void* d_ws, size_t ws_size,
                              hipStream_t stream)
{
    const float* x  = (const float*)d_in[0];
    const float* wq = (const float*)d_in[1];
    const float* bq = (const float*)d_in[2];
    const float* wk = (const float*)d_in[3];
    const float* bk = (const float*)d_in[4];
    const float* wv = (const float*)d_in[5];
    const float* bv = (const float*)d_in[6];
    const float* wo = (const float*)d_in[7];
    const float* bo = (const float*)d_in[8];
    float* out = (float*)d_out;

    const size_t NPIX = (size_t)BATCH * HW;   // 8192
    char* ws  = (char*)d_ws;
    u16* Qh   = (u16*)ws;                      // 8192*96*2  = 1.5 MB
    u16* Kh   = Qh + NPIX * CC;
    u16* Vh   = Kh + NPIX * CC;
    u16* att  = Vh + NPIX * CC;                // 8192*288*2 = 4.7 MB
    float* woT = (float*)(att + NPIX * C3);    // 288*96*4   = 110 KB
    // total ~9.55 MB of d_ws

    transpose_wo<<<dim3((CC * C3 + 255) / 256), 256, 0, stream>>>(wo, woT);

    qkv_kernel<<<dim3(128, 3), 256, 0, stream>>>(x, wq, bq, wk, bk, wv, bv, Qh, Kh, Vh);

    attn_kernel<<<dim3(8, 8, 8), 64, 0, stream>>>(Qh, Kh, Vh, att);

    proj_kernel<<<dim3(128, 2), 256, 0, stream>>>(att, woT, bo, out);
}

// Round 2
// 126.098 us; speedup vs baseline: 1.3484x; 1.3484x over previous
//
#include <hip/hip_runtime.h>
#include <hip/hip_fp16.h>

// DenseMultiRangeAttention on MI355X (gfx950) — round 2: occupancy fixes
// B=2, C=96, H=W=64, heads=4, d=24, ranges {7,9,11}
//
//   K0 prep_w : wo (96x288) f32 -> wh (96x144) packed-f16-pair u32
//   K1 qkv    : x -> Q/K/V (B*HW, 96) f16; x-tile in LDS, 768 blocks
//   K2 attn   : 4 waves/block split 121 neighbor visits by ring,
//               partial (l, acc24) combine via LDS; snapshots 7/9/11
//   K3 proj   : att f16 tile in LDS as u32 pairs, fdot2 vs scalar weights

#define HW    4096
#define NH    4
#define D     24
#define CC    96
#define C3    288
#define BATCH 2

#define TS    8
#define HALO  5
#define SW    18
#define SPIX  324      // SW*SW
#define PSTR  24       // u16 per staged pixel = 48B (stride 12 banks, b128-clean)

#define INV_SCALE 0.20412414523193151f  // 1/sqrt(24)

typedef unsigned short u16;
typedef _Float16 h2f __attribute__((ext_vector_type(2)));

__device__ __forceinline__ float fdot2h(unsigned int a, unsigned int b, float c) {
#if __has_builtin(__builtin_amdgcn_fdot2)
    return __builtin_amdgcn_fdot2(__builtin_bit_cast(h2f, a),
                                  __builtin_bit_cast(h2f, b), c, false);
#else
    float2 fa = __half22float2(__builtin_bit_cast(__half2, a));
    float2 fb = __half22float2(__builtin_bit_cast(__half2, b));
    return fmaf(fa.x, fb.x, fmaf(fa.y, fb.y, c));
#endif
}

__device__ __forceinline__ unsigned int packh2(float a, float b) {
    return __builtin_bit_cast(unsigned int, __floats2half2_rn(a, b));
}

// ---------------------------------------------------------------- K0
// wh[o][c2] = pack(wo[o][2c2], wo[o][2c2+1]); 96x144 u32
__global__ void prep_w(const float* __restrict__ wo, unsigned int* __restrict__ wh) {
    int idx = blockIdx.x * 256 + threadIdx.x;
    if (idx < CC * (C3 / 2)) {
        int o  = idx / (C3 / 2);
        int c2 = idx - o * (C3 / 2);
        wh[idx] = packh2(wo[o * C3 + 2 * c2], wo[o * C3 + 2 * c2 + 1]);
    }
}

// ---------------------------------------------------------------- K1
// grid (128, 3, 2) block 256. Block: 64 px, one matrix, 48 outs (bz half).
// Wave w: outputs o0 = bz*48 + w*12 .. +12 (wave-uniform -> scalar w loads).
__global__ __launch_bounds__(256) void qkv_kernel(
    const float* __restrict__ x,
    const float* __restrict__ wq, const float* __restrict__ bq,
    const float* __restrict__ wk, const float* __restrict__ bk,
    const float* __restrict__ wv, const float* __restrict__ bv,
    u16* __restrict__ Qh, u16* __restrict__ Kh, u16* __restrict__ Vh)
{
    __shared__ __align__(16) float xs[CC * 64];   // 24 KB, [c][px]

    int t   = threadIdx.x;
    int mat = blockIdx.y;
    const float* w    = (mat == 0) ? wq : (mat == 1) ? wk : wv;
    const float* bias = (mat == 0) ? bq : (mat == 1) ? bk : bv;
    u16* dst          = (mat == 0) ? Qh : (mat == 1) ? Kh : Vh;

    int gp0 = blockIdx.x * 64;
    int b   = gp0 >> 12;
    int p0  = gp0 & 4095;

    // stage x tile [96][64] f32 via float4 (fully coalesced)
    const float4* xsrc = (const float4*)(x + (size_t)b * CC * HW + p0);
    #pragma unroll
    for (int k = 0; k < 6; ++k) {
        int u   = t + k * 256;          // 0..1535
        int c   = u >> 4;
        int px4 = u & 15;
        float4 v = xsrc[(size_t)c * (HW / 4) + px4];
        *(float4*)&xs[c * 64 + px4 * 4] = v;
    }
    __syncthreads();

    int wvid = __builtin_amdgcn_readfirstlane(t >> 6);
    int o0   = blockIdx.z * 48 + wvid * 12;
    int px   = t & 63;
    int gp   = gp0 + px;

    float acc[12];
    #pragma unroll
    for (int j = 0; j < 12; ++j) acc[j] = bias[o0 + j];

    #pragma unroll
    for (int cb = 0; cb < 3; ++cb) {
        float xc[32];
        #pragma unroll
        for (int i = 0; i < 32; ++i) xc[i] = xs[(cb * 32 + i) * 64 + px];
        #pragma unroll
        for (int j = 0; j < 12; ++j) {
            const float* wr = w + (o0 + j) * CC + cb * 32;
            #pragma unroll
            for (int i = 0; i < 32; ++i) acc[j] = fmaf(wr[i], xc[i], acc[j]);
        }
    }

    unsigned int u[6];
    #pragma unroll
    for (int i = 0; i < 6; ++i) u[i] = packh2(acc[2 * i], acc[2 * i + 1]);
    uint2* dp = (uint2*)(dst + (size_t)gp * CC + o0);   // 24B offsets: 8B aligned
    dp[0] = make_uint2(u[0], u[1]);
    dp[1] = make_uint2(u[2], u[3]);
    dp[2] = make_uint2(u[4], u[5]);
}

// ---------------------------------------------------------------- K2
// grid (8,8,8) block 256 (4 waves). z = b*4+h. Tile 8x8 px, halo 5.
// Visit split: wv0/wv1 = core 7x7 interleaved (25/24), wv2 = ring->9 (32),
// wv3 = ring->11 (40). Partials combined via LDS (aliased over K/V).
__global__ __launch_bounds__(256) void attn_kernel(
    const u16* __restrict__ Qh, const u16* __restrict__ Kh,
    const u16* __restrict__ Vh, u16* __restrict__ att)
{
    __shared__ __align__(16) u16 smem[2 * SPIX * PSTR];   // 31104 B
    u16* Ks = smem;
    u16* Vs = smem + SPIX * PSTR;
    float* Pb = (float*)smem;        // aliased AFTER visits: [4][64][26] f32 = 26624 B

    int t    = threadIdx.x;
    int wvid = t >> 6, lane = t & 63;
    int bh = blockIdx.z;
    int b  = bh >> 2, h = bh & 3;
    int x0 = blockIdx.x * TS, y0 = blockIdx.y * TS;

    // ---- stage K,V tile (+halo), zeros outside image (matches zero-pad ref)
    for (int sp = t; sp < SPIX; sp += 256) {
        int sy = sp / SW, sx = sp - sy * SW;
        int gy = y0 + sy - HALO, gx = x0 + sx - HALO;
        uint4 k0 = make_uint4(0,0,0,0), k1 = k0, k2 = k0;
        uint4 v0 = k0, v1 = k0, v2 = k0;
        if ((unsigned)gy < 64u && (unsigned)gx < 64u) {
            size_t base = ((size_t)(b * HW + gy * 64 + gx) * CC + h * D);
            const uint4* ksrc = (const uint4*)(Kh + base);
            const uint4* vsrc = (const uint4*)(Vh + base);
            k0 = ksrc[0]; k1 = ksrc[1]; k2 = ksrc[2];
            v0 = vsrc[0]; v1 = vsrc[1]; v2 = vsrc[2];
        }
        uint4* kd = (uint4*)(Ks + sp * PSTR);
        uint4* vd = (uint4*)(Vs + sp * PSTR);
        kd[0] = k0; kd[1] = k1; kd[2] = k2;
        vd[0] = v0; vd[1] = v1; vd[2] = v2;
    }
    __syncthreads();

    int ty = lane >> 3, tx = lane & 7;
    int gp = b * HW + (y0 + ty) * 64 + (x0 + tx);

    unsigned int q[12];
    {
        const uint4* qs = (const uint4*)(Qh + (size_t)gp * CC + h * D);
        uint4 a = qs[0], bb = qs[1], c = qs[2];
        q[0]=a.x;  q[1]=a.y;  q[2]=a.z;  q[3]=a.w;
        q[4]=bb.x; q[5]=bb.y; q[6]=bb.z; q[7]=bb.w;
        q[8]=c.x;  q[9]=c.y;  q[10]=c.z; q[11]=c.w;
    }

    float acc[D];
    #pragma unroll
    for (int j = 0; j < D; ++j) acc[j] = 0.f;
    float l  = 0.f;
    int   cp = (ty + HALO) * SW + (tx + HALO);

    auto visit = [&](int di, int dj) {
        int sp = cp + di * SW + dj;
        const uint4* kp = (const uint4*)(Ks + sp * PSTR);
        uint4 k0 = kp[0], k1 = kp[1], k2 = kp[2];
        unsigned int ku[12] = {k0.x,k0.y,k0.z,k0.w, k1.x,k1.y,k1.z,k1.w, k2.x,k2.y,k2.z,k2.w};
        float s = 0.f;
        #pragma unroll
        for (int i = 0; i < 12; ++i) s = fdot2h(ku[i], q[i], s);
        float pw = __expf(s * INV_SCALE);
        l += pw;
        const uint4* vp = (const uint4*)(Vs + sp * PSTR);
        uint4 v0 = vp[0], v1 = vp[1], v2 = vp[2];
        unsigned int vu[12] = {v0.x,v0.y,v0.z,v0.w, v1.x,v1.y,v1.z,v1.w, v2.x,v2.y,v2.z,v2.w};
        #pragma unroll
        for (int i = 0; i < 12; ++i) {
            float2 f = __half22float2(__builtin_bit_cast(__half2, vu[i]));
            acc[2*i]   = fmaf(pw, f.x, acc[2*i]);
            acc[2*i+1] = fmaf(pw, f.y, acc[2*i+1]);
        }
    };

    if (wvid == 0) {
        #pragma unroll
        for (int k = 0; k < 49; k += 2) visit(k / 7 - 3, k % 7 - 3);
    } else if (wvid == 1) {
        #pragma unroll
        for (int k = 1; k < 49; k += 2) visit(k / 7 - 3, k % 7 - 3);
    } else if (wvid == 2) {
        #pragma unroll
        for (int dj = -4; dj <= 4; ++dj) { visit(-4, dj); visit(4, dj); }
        #pragma unroll
        for (int di = -3; di <= 3; ++di) { visit(di, -4); visit(di, 4); }
    } else {
        #pragma unroll
        for (int dj = -5; dj <= 5; ++dj) { visit(-5, dj); visit(5, dj); }
        #pragma unroll
        for (int di = -4; di <= 4; ++di) { visit(di, -5); visit(di, 5); }
    }

    __syncthreads();                 // all visits done; K/V dead -> alias Pb
    {
        float* pp = Pb + (wvid * 64 + lane) * 26;
        pp[0] = l;
        #pragma unroll
        for (int i = 0; i < D; ++i) pp[1 + i] = acc[i];
    }
    __syncthreads();

    // wave r in {0,1,2} combines partials {0..r+1} and writes range r
    if (wvid < 3) {
        float L = 0.f;
        float a[D];
        #pragma unroll
        for (int i = 0; i < D; ++i) a[i] = 0.f;
        #pragma unroll
        for (int s = 0; s < 4; ++s) {
            if (s <= wvid + 1) {
                const float* pp = Pb + (s * 64 + lane) * 26;
                L += pp[0];
                #pragma unroll
                for (int i = 0; i < D; ++i) a[i] += pp[1 + i];
            }
        }
        float rl = 1.0f / L;
        unsigned int u[12];
        #pragma unroll
        for (int i = 0; i < 12; ++i)
            u[i] = packh2(a[2 * i] * rl, a[2 * i + 1] * rl);
        uint4* dp = (uint4*)(att + (size_t)gp * C3 + h * 72 + wvid * D);
        dp[0] = make_uint4(u[0], u[1], u[2],  u[3]);
        dp[1] = make_uint4(u[4], u[5], u[6],  u[7]);
        dp[2] = make_uint4(u[8], u[9], u[10], u[11]);
    }
}

// ---------------------------------------------------------------- K3
// grid (128, 4) block 256. 64 px/block, 24 outs/block (6 per wave).
// att tile staged as u32 f16-pairs [144][65] (pad kills bank conflicts).
#define K3_PAD 65
__global__ __launch_bounds__(256) void proj_kernel(
    const u16* __restrict__ att, const unsigned int* __restrict__ wh,
    const float* __restrict__ bo, float* __restrict__ out)
{
    __shared__ unsigned int ab[(C3 / 2) * K3_PAD];   // 144*65*4 = 37440 B

    int t   = threadIdx.x;
    int gp0 = blockIdx.x * 64;

    const uint4* src = (const uint4*)(att + (size_t)gp0 * C3);
    #pragma unroll
    for (int k = 0; k < 9; ++k) {
        int u   = t + k * 256;        // 0..2303 ; 36 uint4 per pixel
        uint4 v = src[u];
        int px  = u / 36;
        int c20 = (u - px * 36) * 4;
        ab[(c20    ) * K3_PAD + px] = v.x;
        ab[(c20 + 1) * K3_PAD + px] = v.y;
        ab[(c20 + 2) * K3_PAD + px] = v.z;
        ab[(c20 + 3) * K3_PAD + px] = v.w;
    }
    __syncthreads();

    int wvid = __builtin_amdgcn_readfirstlane(t >> 6);
    int o0   = blockIdx.y * 24 + wvid * 6;
    int px   = t & 63;
    int gp   = gp0 + px;
    int b    = gp >> 12, p = gp & 4095;

    float acc[6];
    #pragma unroll
    for (int j = 0; j < 6; ++j) acc[j] = bo[o0 + j];

    #pragma unroll
    for (int cb = 0; cb < 9; ++cb) {
        unsigned int xp[16];
        #pragma unroll
        for (int i = 0; i < 16; ++i) xp[i] = ab[(cb * 16 + i) * K3_PAD + px];
        #pragma unroll
        for (int j = 0; j < 6; ++j) {
            const unsigned int* wr = wh + (o0 + j) * (C3 / 2) + cb * 16;
            #pragma unroll
            for (int i = 0; i < 16; ++i) acc[j] = fdot2h(xp[i], wr[i], acc[j]);
        }
    }

    #pragma unroll
    for (int j = 0; j < 6; ++j)
        out[(size_t)(b * CC + o0 + j) * HW + p] = acc[j];
}

// ---------------------------------------------------------------- launch
extern "C" void kernel_launch(void* const* d_in, const int* in_sizes, int n_in,
                              void* d_out, int out_size, void* d_ws, size_t ws_size,
                              hipStream_t stream)
{
    const float* x  = (const float*)d_in[0];
    const float* wq = (const float*)d_in[1];
    const float* bq = (const float*)d_in[2];
    const float* wk = (const float*)d_in[3];
    const float* bk = (const float*)d_in[4];
    const float* wv = (const float*)d_in[5];
    const float* bv = (const float*)d_in[6];
    const float* wo = (const float*)d_in[7];
    const float* bo = (const float*)d_in[8];
    float* out = (float*)d_out;

    const size_t NPIX = (size_t)BATCH * HW;     // 8192
    char* ws = (char*)d_ws;
    u16* Qh  = (u16*)ws;                        // 1.5 MB
    u16* Kh  = Qh + NPIX * CC;
    u16* Vh  = Kh + NPIX * CC;
    u16* att = Vh + NPIX * CC;                  // 4.7 MB
    unsigned int* wh = (unsigned int*)(att + NPIX * C3);  // 96*144*4 = 55 KB

    prep_w<<<dim3(54), 256, 0, stream>>>(wo, wh);

    qkv_kernel<<<dim3(128, 3, 2), 256, 0, stream>>>(x, wq, bq, wk, bk, wv, bv, Qh, Kh, Vh);

    attn_kernel<<<dim3(8, 8, 8), 256, 0, stream>>>(Qh, Kh, Vh, att);

    proj_kernel<<<dim3(128, 4), 256, 0, stream>>>(att, wh, bo, out);
}